// Round 4
// baseline (1974.946 us; speedup 1.0000x reference)
//
#include <hip/hip_runtime.h>

#define IN_DIM 256
#define HID 64
#define BSH 6              // log2(nodes per coarse bucket)
#define BNODES 64          // nodes per bucket

// ---------------------------------------------------------------------------
// 1) cnt[i] = 0
__global__ void __launch_bounds__(256) k_zero(int* __restrict__ cnt, int N) {
    int i = blockIdx.x * 256 + threadIdx.x;
    int stride = gridDim.x * 256;
    for (; i < N; i += stride) cnt[i] = 0;
}

// 2) histogram of destinations: cnt[col[e]]++
__global__ void __launch_bounds__(256) k_hist(const int* __restrict__ col,
                                              int* __restrict__ cnt, int E) {
    int i = blockIdx.x * 256 + threadIdx.x;
    int stride = gridDim.x * 256;
    for (; i < E; i += stride) atomicAdd(&cnt[col[i]], 1);
}

// 3) per-bucket edge counts (wave per bucket, shfl reduce) + dinv = rsqrt(deg+1)
__global__ void __launch_bounds__(256) k_bcnt_dinv(const int* __restrict__ cnt,
                                                   int* __restrict__ bucketCnt,
                                                   float* __restrict__ dinv, int N, int NB) {
    const int wave = threadIdx.x >> 6, lane = threadIdx.x & 63;
    const int b = blockIdx.x * 4 + wave;
    if (b >= NB) return;
    const int n = (b << BSH) + lane;
    int c = (n < N) ? cnt[n] : 0;
    if (n < N) dinv[n] = __frsqrt_rn((float)(c + 1));
    int s = c;
    for (int m = 1; m < 64; m <<= 1) s += __shfl_xor(s, m, 64);
    if (lane == 0) bucketCnt[b] = s;
}

// 4) single-block exclusive scan of bucketCnt[NB] -> bucketOff[NB+1] + cursor copy
__global__ void __launch_bounds__(256) k_scanB(const int* __restrict__ bucketCnt,
                                               int* __restrict__ bucketOff,
                                               int* __restrict__ cursor, int NB, int E) {
    __shared__ int tmp[256];
    const int tid = threadIdx.x;
    const int PT = (NB + 255) >> 8;  // <= 8 for N <= 131072
    int v[8];
    int s = 0;
    for (int k = 0; k < PT; ++k) {
        int i = tid * PT + k;
        v[k] = (i < NB) ? bucketCnt[i] : 0;
        s += v[k];
    }
    tmp[tid] = s;
    __syncthreads();
    for (int d = 1; d < 256; d <<= 1) {  // Hillis-Steele inclusive scan
        int val = (tid >= d) ? tmp[tid - d] : 0;
        __syncthreads();
        tmp[tid] += val;
        __syncthreads();
    }
    int run = tmp[tid] - s;
    for (int k = 0; k < PT; ++k) {
        int i = tid * PT + k;
        if (i < NB) { bucketOff[i] = run; cursor[i] = run; }
        run += v[k];
    }
    if (tid == 255) bucketOff[NB] = E;
}

// 5) xs = (x @ W) * dinv[n]   — register-tiled fp32 GEMM (unchanged from R2)
__global__ void __launch_bounds__(256) k_gemm(const float* __restrict__ x,
                                              const float* __restrict__ W,
                                              const float* __restrict__ dinv,
                                              float* __restrict__ xs, int N) {
    __shared__ float xT[32][260];
    __shared__ float Wl[32][64];
    const int t = threadIdx.x;
    const int tmI = t >> 3;
    const int tnI = t & 7;
    const int nodeBase = blockIdx.x * 256;

    float acc[8][8] = {};

    for (int k0 = 0; k0 < IN_DIM; k0 += 32) {
#pragma unroll
        for (int i = 0; i < 2; ++i) {
            int flat = i * 256 + t;
            float4 wv = ((const float4*)W)[k0 * 16 + flat];
            *(float4*)&Wl[flat >> 4][(flat & 15) << 2] = wv;
        }
#pragma unroll
        for (int i = 0; i < 8; ++i) {
            int flat = i * 256 + t;
            int n = flat >> 3;
            int kq = (flat & 7) << 2;
            int gn = nodeBase + n;
            if (gn >= N) gn = N - 1;
            float4 v = *(const float4*)(x + (size_t)gn * IN_DIM + k0 + kq);
            xT[kq + 0][n] = v.x;
            xT[kq + 1][n] = v.y;
            xT[kq + 2][n] = v.z;
            xT[kq + 3][n] = v.w;
        }
        __syncthreads();
#pragma unroll
        for (int k = 0; k < 32; ++k) {
            float xv[8], wv[8];
            *(float4*)&xv[0] = *(const float4*)&xT[k][tmI * 8];
            *(float4*)&xv[4] = *(const float4*)&xT[k][tmI * 8 + 4];
            *(float4*)&wv[0] = *(const float4*)&Wl[k][tnI * 8];
            *(float4*)&wv[4] = *(const float4*)&Wl[k][tnI * 8 + 4];
#pragma unroll
            for (int mi = 0; mi < 8; ++mi)
#pragma unroll
                for (int ni = 0; ni < 8; ++ni)
                    acc[mi][ni] = fmaf(xv[mi], wv[ni], acc[mi][ni]);
        }
        __syncthreads();
    }

#pragma unroll
    for (int mi = 0; mi < 8; ++mi) {
        int n = nodeBase + tmI * 8 + mi;
        if (n < N) {
            float d = dinv[n];
            float* dst = xs + (size_t)n * HID + tnI * 8;
            float4 o;
            o.x = acc[mi][0] * d; o.y = acc[mi][1] * d;
            o.z = acc[mi][2] * d; o.w = acc[mi][3] * d;
            *(float4*)dst = o;
            o.x = acc[mi][4] * d; o.y = acc[mi][5] * d;
            o.z = acc[mi][6] * d; o.w = acc[mi][7] * d;
            *(float4*)(dst + 4) = o;
        }
    }
}

// 6) partition edges into coarse buckets: part[cursor[col>>6]++] = (row<<6)|(col&63)
//    Hot cursor regions (1563 x 64B ~ 100KB) stay L2-resident -> full-line writes.
__global__ void __launch_bounds__(256) k_partition(const int* __restrict__ row,
                                                   const int* __restrict__ col,
                                                   int* __restrict__ cursor,
                                                   int* __restrict__ part, int E) {
    int i = blockIdx.x * 256 + threadIdx.x;
    int stride = gridDim.x * 256;
    for (; i < E; i += stride) {
        int c = col[i], r = row[i];
        int pos = atomicAdd(&cursor[c >> BSH], 1);
        part[pos] = (r << BSH) | (c & (BNODES - 1));
    }
}

// 7) block-per-bucket aggregate: LDS acc[64 nodes][64 cols], ds_add_f32 per edge,
//    fused epilogue out = relu(dinv*(acc + xs_self) + b). No global atomics.
__global__ void __launch_bounds__(256) k_agg2(const int* __restrict__ bucketOff,
                                              const int* __restrict__ part,
                                              const float* __restrict__ xs,
                                              const float* __restrict__ dinv,
                                              const float* __restrict__ bias,
                                              float* __restrict__ out, int N) {
    __shared__ float acc[BNODES * HID];  // 16 KB
    const int b = blockIdx.x;
    const int wave = threadIdx.x >> 6, lane = threadIdx.x & 63;

    for (int i = threadIdx.x; i < BNODES * HID / 4; i += 256)
        ((float4*)acc)[i] = float4{0.f, 0.f, 0.f, 0.f};
    __syncthreads();

    const int s = bucketOff[b], t = bucketOff[b + 1];
    const int cntb = t - s, per = (cntb + 3) >> 2;
    int j = s + wave * per;
    const int je = min(j + per, t);
    for (; j + 1 < je; j += 2) {  // 2-wide for gather ILP
        int p0 = part[j], p1 = part[j + 1];
        float v0 = xs[(size_t)(p0 >> BSH) * HID + lane];
        float v1 = xs[(size_t)(p1 >> BSH) * HID + lane];
        atomicAdd(&acc[(p0 & (BNODES - 1)) * HID + lane], v0);
        atomicAdd(&acc[(p1 & (BNODES - 1)) * HID + lane], v1);
    }
    if (j < je) {
        int p0 = part[j];
        atomicAdd(&acc[(p0 & (BNODES - 1)) * HID + lane],
                  xs[(size_t)(p0 >> BSH) * HID + lane]);
    }
    __syncthreads();

    const float bl = bias[lane];
    const int nodeBase = b << BSH;
#pragma unroll
    for (int i = 0; i < 16; ++i) {
        int ln = wave * 16 + i;
        int n = nodeBase + ln;
        if (n < N) {
            float v = acc[ln * HID + lane] + xs[(size_t)n * HID + lane];
            out[(size_t)n * HID + lane] = fmaxf(fmaf(v, dinv[n], bl), 0.f);
        }
    }
}

extern "C" void kernel_launch(void* const* d_in, const int* in_sizes, int n_in,
                              void* d_out, int out_size, void* d_ws, size_t ws_size,
                              hipStream_t stream) {
    const float* x  = (const float*)d_in[0];
    const int*   ei = (const int*)d_in[1];
    const float* W  = (const float*)d_in[2];
    const float* b  = (const float*)d_in[3];
    float* out = (float*)d_out;

    const int N = in_sizes[0] / IN_DIM;
    const int E = in_sizes[1] / 2;
    const int* row = ei;      // edge_index[0] = sources
    const int* col = ei + E;  // edge_index[1] = destinations
    const int NB = (N + BNODES - 1) >> BSH;

    // workspace (4-byte units):
    // cnt[N] | bucketCnt[NB] | bucketOff[NB+1] | cursor[NB] | dinv[N] | xs[N*HID] | part[E]
    int*   cnt       = (int*)d_ws;
    int*   bucketCnt = cnt + N;
    int*   bucketOff = bucketCnt + NB;
    int*   cursor    = bucketOff + NB + 1;
    float* dinv      = (float*)(cursor + NB);
    float* xs        = dinv + N;
    int*   part      = (int*)(xs + (size_t)N * HID);

    k_zero<<<(N + 255) / 256, 256, 0, stream>>>(cnt, N);
    k_hist<<<2048, 256, 0, stream>>>(col, cnt, E);
    k_bcnt_dinv<<<(NB + 3) / 4, 256, 0, stream>>>(cnt, bucketCnt, dinv, N, NB);
    k_scanB<<<1, 256, 0, stream>>>(bucketCnt, bucketOff, cursor, NB, E);
    k_gemm<<<(N + 255) / 256, 256, 0, stream>>>(x, W, dinv, xs, N);
    k_partition<<<2048, 256, 0, stream>>>(row, col, cursor, part, E);
    k_agg2<<<NB, 256, 0, stream>>>(bucketOff, part, xs, dinv, b, out, N);
}

// Round 5
// 970.800 us; speedup vs baseline: 2.0343x; 2.0343x over previous
//
#include <hip/hip_runtime.h>

#define IN_DIM 256
#define HID 64
#define BSH 6              // log2(nodes per coarse bucket)
#define BNODES 64          // nodes per bucket
#define CHUNK 2048         // elements per block in k_scan1 (256 thr x 8)

// ---------------------------------------------------------------------------
// 1) cnt[i] = 0
__global__ void __launch_bounds__(256) k_zero(int* __restrict__ cnt, int N) {
    int i = blockIdx.x * 256 + threadIdx.x;
    int stride = gridDim.x * 256;
    for (; i < N; i += stride) cnt[i] = 0;
}

// 2) histogram of destinations: cnt[col[e]]++
__global__ void __launch_bounds__(256) k_hist(const int* __restrict__ col,
                                              int* __restrict__ cnt, int E) {
    int i = blockIdx.x * 256 + threadIdx.x;
    int stride = gridDim.x * 256;
    for (; i < E; i += stride) atomicAdd(&cnt[col[i]], 1);
}

// 3a) per-chunk exclusive partial scan + chunk sums
__global__ void __launch_bounds__(256) k_scan1(const int* __restrict__ cnt,
                                               int* __restrict__ pscan,
                                               int* __restrict__ chunkSum, int N) {
    __shared__ int tmp[256];
    const int tid = threadIdx.x;
    const int base = blockIdx.x * CHUNK + tid * 8;
    int v[8];
    int s = 0;
#pragma unroll
    for (int t = 0; t < 8; ++t) {
        int i = base + t;
        v[t] = (i < N) ? cnt[i] : 0;
        s += v[t];
    }
    tmp[tid] = s;
    __syncthreads();
    for (int d = 1; d < 256; d <<= 1) {  // Hillis-Steele inclusive scan
        int val = (tid >= d) ? tmp[tid - d] : 0;
        __syncthreads();
        tmp[tid] += val;
        __syncthreads();
    }
    int run = tmp[tid] - s;  // exclusive base for this thread
#pragma unroll
    for (int t = 0; t < 8; ++t) {
        int i = base + t;
        if (i < N) pscan[i] = run;
        run += v[t];
    }
    if (tid == 255) chunkSum[blockIdx.x] = tmp[255];
}

// 3b) serial scan of chunk sums (~49 entries)
__global__ void k_scan2(const int* __restrict__ chunkSum, int* __restrict__ chunkOff, int nch) {
    if (threadIdx.x == 0 && blockIdx.x == 0) {
        int run = 0;
        for (int c = 0; c < nch; ++c) { chunkOff[c] = run; run += chunkSum[c]; }
    }
}

// 3c) finalize fine rowptr, bucket cursors (= rowptr at bucket starts), dinv
__global__ void __launch_bounds__(256) k_scan3(const int* __restrict__ cnt,
                                               const int* __restrict__ pscan,
                                               const int* __restrict__ chunkOff,
                                               int* __restrict__ rowptr,
                                               int* __restrict__ cursorB,
                                               float* __restrict__ dinv, int N, int E) {
    int i = blockIdx.x * 256 + threadIdx.x;
    int stride = gridDim.x * 256;
    for (; i < N; i += stride) {
        int r = pscan[i] + chunkOff[i >> 11];  // CHUNK = 2048 = 1<<11
        rowptr[i] = r;
        if ((i & (BNODES - 1)) == 0) cursorB[i >> BSH] = r;
        dinv[i] = __frsqrt_rn((float)(cnt[i] + 1));
    }
    if (blockIdx.x == 0 && threadIdx.x == 0) rowptr[N] = E;
}

// 4) xs = (x @ W) * dinv[n]   — register-tiled fp32 GEMM (proven R2)
__global__ void __launch_bounds__(256) k_gemm(const float* __restrict__ x,
                                              const float* __restrict__ W,
                                              const float* __restrict__ dinv,
                                              float* __restrict__ xs, int N) {
    __shared__ float xT[32][260];
    __shared__ float Wl[32][64];
    const int t = threadIdx.x;
    const int tmI = t >> 3;
    const int tnI = t & 7;
    const int nodeBase = blockIdx.x * 256;

    float acc[8][8] = {};

    for (int k0 = 0; k0 < IN_DIM; k0 += 32) {
#pragma unroll
        for (int i = 0; i < 2; ++i) {
            int flat = i * 256 + t;
            float4 wv = ((const float4*)W)[k0 * 16 + flat];
            *(float4*)&Wl[flat >> 4][(flat & 15) << 2] = wv;
        }
#pragma unroll
        for (int i = 0; i < 8; ++i) {
            int flat = i * 256 + t;
            int n = flat >> 3;
            int kq = (flat & 7) << 2;
            int gn = nodeBase + n;
            if (gn >= N) gn = N - 1;
            float4 v = *(const float4*)(x + (size_t)gn * IN_DIM + k0 + kq);
            xT[kq + 0][n] = v.x;
            xT[kq + 1][n] = v.y;
            xT[kq + 2][n] = v.z;
            xT[kq + 3][n] = v.w;
        }
        __syncthreads();
#pragma unroll
        for (int k = 0; k < 32; ++k) {
            float xv[8], wv[8];
            *(float4*)&xv[0] = *(const float4*)&xT[k][tmI * 8];
            *(float4*)&xv[4] = *(const float4*)&xT[k][tmI * 8 + 4];
            *(float4*)&wv[0] = *(const float4*)&Wl[k][tnI * 8];
            *(float4*)&wv[4] = *(const float4*)&Wl[k][tnI * 8 + 4];
#pragma unroll
            for (int mi = 0; mi < 8; ++mi)
#pragma unroll
                for (int ni = 0; ni < 8; ++ni)
                    acc[mi][ni] = fmaf(xv[mi], wv[ni], acc[mi][ni]);
        }
        __syncthreads();
    }

#pragma unroll
    for (int mi = 0; mi < 8; ++mi) {
        int n = nodeBase + tmI * 8 + mi;
        if (n < N) {
            float d = dinv[n];
            float* dst = xs + (size_t)n * HID + tnI * 8;
            float4 o;
            o.x = acc[mi][0] * d; o.y = acc[mi][1] * d;
            o.z = acc[mi][2] * d; o.w = acc[mi][3] * d;
            *(float4*)dst = o;
            o.x = acc[mi][4] * d; o.y = acc[mi][5] * d;
            o.z = acc[mi][6] * d; o.w = acc[mi][7] * d;
            *(float4*)(dst + 4) = o;
        }
    }
}

// 5) partition edges into coarse buckets: part[cursorB[col>>6]++] = (row<<6)|(col&63)
//    Hot cursor/write regions (1563) stay L2-resident -> full-line writes.
__global__ void __launch_bounds__(256) k_partition(const int* __restrict__ row,
                                                   const int* __restrict__ col,
                                                   int* __restrict__ cursorB,
                                                   int* __restrict__ part, int E) {
    int i = blockIdx.x * 256 + threadIdx.x;
    int stride = gridDim.x * 256;
    for (; i < E; i += stride) {
        int c = col[i], r = row[i];
        int pos = atomicAdd(&cursorB[c >> BSH], 1);
        part[pos] = (r << BSH) | (c & (BNODES - 1));
    }
}

// 6) within-bucket counting sort -> eRow fully sorted by destination.
//    Block owns its bucket exclusively: LDS cursors, writes confined to the
//    bucket's contiguous ~8KB range (no global atomics, no write amplification).
__global__ void __launch_bounds__(256) k_binsort(const int* __restrict__ rowptr,
                                                 const int* __restrict__ part,
                                                 int* __restrict__ eRow, int N, int E) {
    __shared__ int lbase[BNODES];
    __shared__ int lcur[BNODES];
    const int b = blockIdx.x;
    const int base = b << BSH;
    if (threadIdx.x < BNODES) {
        int n = base + threadIdx.x;
        lbase[threadIdx.x] = (n < N) ? rowptr[n] : E;
        lcur[threadIdx.x] = 0;
    }
    __syncthreads();
    const int s = rowptr[base];
    const int e = (base + BNODES <= N) ? rowptr[base + BNODES] : E;
    for (int j = s + threadIdx.x; j < e; j += 256) {
        int p = part[j];
        int nl = p & (BNODES - 1);
        int pos = lbase[nl] + atomicAdd(&lcur[nl], 1);
        eRow[pos] = p >> BSH;
    }
}

// 7) gather-aggregate (proven R3): wave per node, lane = hidden column.
__global__ void __launch_bounds__(256) k_aggregate(const int* __restrict__ rowptr,
                                                   const int* __restrict__ eRow,
                                                   const float* __restrict__ xs,
                                                   const float* __restrict__ dinv,
                                                   const float* __restrict__ b,
                                                   float* __restrict__ out, int N) {
    const int lane = threadIdx.x & 63;
    const int n = blockIdx.x * 4 + (threadIdx.x >> 6);
    if (n >= N) return;
    const float bl = b[lane];

    const int s = rowptr[n];
    const int e = rowptr[n + 1];
    float acc = xs[(size_t)n * HID + lane];  // self-loop (xs already has dinv[n])
    float a0 = 0.f, a1 = 0.f, a2 = 0.f, a3 = 0.f;
    int j = s;
    for (; j + 3 < e; j += 4) {
        int r0 = eRow[j], r1 = eRow[j + 1], r2 = eRow[j + 2], r3 = eRow[j + 3];
        a0 += xs[(size_t)r0 * HID + lane];
        a1 += xs[(size_t)r1 * HID + lane];
        a2 += xs[(size_t)r2 * HID + lane];
        a3 += xs[(size_t)r3 * HID + lane];
    }
    for (; j < e; ++j) acc += xs[(size_t)eRow[j] * HID + lane];
    acc += (a0 + a1) + (a2 + a3);

    out[(size_t)n * HID + lane] = fmaxf(fmaf(acc, dinv[n], bl), 0.f);
}

extern "C" void kernel_launch(void* const* d_in, const int* in_sizes, int n_in,
                              void* d_out, int out_size, void* d_ws, size_t ws_size,
                              hipStream_t stream) {
    const float* x  = (const float*)d_in[0];
    const int*   ei = (const int*)d_in[1];
    const float* W  = (const float*)d_in[2];
    const float* b  = (const float*)d_in[3];
    float* out = (float*)d_out;

    const int N = in_sizes[0] / IN_DIM;
    const int E = in_sizes[1] / 2;
    const int* row = ei;      // edge_index[0] = sources
    const int* col = ei + E;  // edge_index[1] = destinations
    const int NB = (N + BNODES - 1) >> BSH;
    const int nch = (N + CHUNK - 1) / CHUNK;

    // workspace (4-byte units), ~53 MB:
    // cnt[N] | pscan[N] | rowptr[N+1] | cursorB[NB] | chunkSum[64] | chunkOff[64]
    // | dinv[N] | xs[N*HID] | part[E] | eRow[E]
    int*   cnt      = (int*)d_ws;
    int*   pscan    = cnt + N;
    int*   rowptr   = pscan + N;
    int*   cursorB  = rowptr + (N + 1);
    int*   chunkSum = cursorB + NB;
    int*   chunkOff = chunkSum + 64;
    float* dinv     = (float*)(chunkOff + 64);
    float* xs       = dinv + N;
    int*   part     = (int*)(xs + (size_t)N * HID);
    int*   eRow     = part + E;

    k_zero<<<(N + 255) / 256, 256, 0, stream>>>(cnt, N);
    k_hist<<<2048, 256, 0, stream>>>(col, cnt, E);
    k_scan1<<<nch, 256, 0, stream>>>(cnt, pscan, chunkSum, N);
    k_scan2<<<1, 64, 0, stream>>>(chunkSum, chunkOff, nch);
    k_scan3<<<(N + 255) / 256, 256, 0, stream>>>(cnt, pscan, chunkOff, rowptr, cursorB, dinv, N, E);
    k_gemm<<<(N + 255) / 256, 256, 0, stream>>>(x, W, dinv, xs, N);
    k_partition<<<2048, 256, 0, stream>>>(row, col, cursorB, part, E);
    k_binsort<<<NB, 256, 0, stream>>>(rowptr, part, eRow, N, E);
    k_aggregate<<<(N + 3) / 4, 256, 0, stream>>>(rowptr, eRow, xs, dinv, b, out, N);
}

// Round 6
// 522.032 us; speedup vs baseline: 3.7832x; 1.8597x over previous
//
#include <hip/hip_runtime.h>

#define IN_DIM 256
#define HID 64
#define SBSH 8             // log2(nodes per super-bucket)
#define SBN 256            // nodes per super-bucket
#define NSB_MAX 512        // LDS array bound (covers N <= 131072)
#define CHUNK 2048         // elements per block in k_scan1 (256 thr x 8)

// round-to-nearest-even fp32 -> bf16 bits
static __device__ __forceinline__ unsigned bf16r(float f) {
    unsigned x = __float_as_uint(f);
    return (x + 0x7fffu + ((x >> 16) & 1u)) >> 16;
}

// ---------------------------------------------------------------------------
// 1) cnt[i] = 0
__global__ void __launch_bounds__(256) k_zero(int* __restrict__ cnt, int N) {
    int i = blockIdx.x * 256 + threadIdx.x;
    int stride = gridDim.x * 256;
    for (; i < N; i += stride) cnt[i] = 0;
}

// 2) histogram of destinations: cnt[col[e]]++
__global__ void __launch_bounds__(256) k_hist(const int* __restrict__ col,
                                              int* __restrict__ cnt, int E) {
    int i = blockIdx.x * 256 + threadIdx.x;
    int stride = gridDim.x * 256;
    for (; i < E; i += stride) atomicAdd(&cnt[col[i]], 1);
}

// 3a) per-chunk exclusive partial scan + chunk sums
__global__ void __launch_bounds__(256) k_scan1(const int* __restrict__ cnt,
                                               int* __restrict__ pscan,
                                               int* __restrict__ chunkSum, int N) {
    __shared__ int tmp[256];
    const int tid = threadIdx.x;
    const int base = blockIdx.x * CHUNK + tid * 8;
    int v[8];
    int s = 0;
#pragma unroll
    for (int t = 0; t < 8; ++t) {
        int i = base + t;
        v[t] = (i < N) ? cnt[i] : 0;
        s += v[t];
    }
    tmp[tid] = s;
    __syncthreads();
    for (int d = 1; d < 256; d <<= 1) {  // Hillis-Steele inclusive scan
        int val = (tid >= d) ? tmp[tid - d] : 0;
        __syncthreads();
        tmp[tid] += val;
        __syncthreads();
    }
    int run = tmp[tid] - s;
#pragma unroll
    for (int t = 0; t < 8; ++t) {
        int i = base + t;
        if (i < N) pscan[i] = run;
        run += v[t];
    }
    if (tid == 255) chunkSum[blockIdx.x] = tmp[255];
}

// 3b) serial scan of chunk sums (~49 entries)
__global__ void k_scan2(const int* __restrict__ chunkSum, int* __restrict__ chunkOff, int nch) {
    if (threadIdx.x == 0 && blockIdx.x == 0) {
        int run = 0;
        for (int c = 0; c < nch; ++c) { chunkOff[c] = run; run += chunkSum[c]; }
    }
}

// 3c) finalize fine rowptr, super-bucket cursors, dinv = rsqrt(deg+1)
__global__ void __launch_bounds__(256) k_scan3(const int* __restrict__ cnt,
                                               const int* __restrict__ pscan,
                                               const int* __restrict__ chunkOff,
                                               int* __restrict__ rowptr,
                                               int* __restrict__ cursorB,
                                               float* __restrict__ dinv, int N, int E) {
    int i = blockIdx.x * 256 + threadIdx.x;
    int stride = gridDim.x * 256;
    for (; i < N; i += stride) {
        int r = pscan[i] + chunkOff[i >> 11];  // CHUNK = 2048 = 1<<11
        rowptr[i] = r;
        if ((i & (SBN - 1)) == 0) cursorB[i >> SBSH] = r;
        dinv[i] = __frsqrt_rn((float)(cnt[i] + 1));
    }
    if (blockIdx.x == 0 && threadIdx.x == 0) rowptr[N] = E;
}

// 4) xs = (x @ W) * dinv[n]  — register-tiled fp32 GEMM; epilogue packs bf16x2.
__global__ void __launch_bounds__(256) k_gemm(const float* __restrict__ x,
                                              const float* __restrict__ W,
                                              const float* __restrict__ dinv,
                                              unsigned* __restrict__ xsb, int N) {
    __shared__ float xT[32][260];
    __shared__ float Wl[32][64];
    const int t = threadIdx.x;
    const int tmI = t >> 3;
    const int tnI = t & 7;
    const int nodeBase = blockIdx.x * 256;

    float acc[8][8] = {};

    for (int k0 = 0; k0 < IN_DIM; k0 += 32) {
#pragma unroll
        for (int i = 0; i < 2; ++i) {
            int flat = i * 256 + t;
            float4 wv = ((const float4*)W)[k0 * 16 + flat];
            *(float4*)&Wl[flat >> 4][(flat & 15) << 2] = wv;
        }
#pragma unroll
        for (int i = 0; i < 8; ++i) {
            int flat = i * 256 + t;
            int n = flat >> 3;
            int kq = (flat & 7) << 2;
            int gn = nodeBase + n;
            if (gn >= N) gn = N - 1;
            float4 v = *(const float4*)(x + (size_t)gn * IN_DIM + k0 + kq);
            xT[kq + 0][n] = v.x;
            xT[kq + 1][n] = v.y;
            xT[kq + 2][n] = v.z;
            xT[kq + 3][n] = v.w;
        }
        __syncthreads();
#pragma unroll
        for (int k = 0; k < 32; ++k) {
            float xv[8], wv[8];
            *(float4*)&xv[0] = *(const float4*)&xT[k][tmI * 8];
            *(float4*)&xv[4] = *(const float4*)&xT[k][tmI * 8 + 4];
            *(float4*)&wv[0] = *(const float4*)&Wl[k][tnI * 8];
            *(float4*)&wv[4] = *(const float4*)&Wl[k][tnI * 8 + 4];
#pragma unroll
            for (int mi = 0; mi < 8; ++mi)
#pragma unroll
                for (int ni = 0; ni < 8; ++ni)
                    acc[mi][ni] = fmaf(xv[mi], wv[ni], acc[mi][ni]);
        }
        __syncthreads();
    }

#pragma unroll
    for (int mi = 0; mi < 8; ++mi) {
        int n = nodeBase + tmI * 8 + mi;
        if (n < N) {
            float d = dinv[n];
            uint4 o;
            o.x = bf16r(acc[mi][0] * d) | (bf16r(acc[mi][1] * d) << 16);
            o.y = bf16r(acc[mi][2] * d) | (bf16r(acc[mi][3] * d) << 16);
            o.z = bf16r(acc[mi][4] * d) | (bf16r(acc[mi][5] * d) << 16);
            o.w = bf16r(acc[mi][6] * d) | (bf16r(acc[mi][7] * d) << 16);
            *(uint4*)(xsb + (size_t)n * (HID / 2) + tnI * 4) = o;
        }
    }
}

// 5) two-pass per-block LDS-histogram partition into 256-node super-buckets.
//    Global cursor atomics: one per (block, bucket) = ~100K total (vs 3.2M).
//    part[pos] = (row << 8) | (col & 255); runs are ~128B single-writer.
__global__ void __launch_bounds__(256) k_part2(const int* __restrict__ row,
                                               const int* __restrict__ col,
                                               int* __restrict__ cursorB,
                                               int* __restrict__ part, int E, int nsb) {
    __shared__ int hist[NSB_MAX];
    __shared__ int lcur[NSB_MAX];
    const int tid = threadIdx.x;
    const int chunkE = (E + gridDim.x - 1) / gridDim.x;
    const int s = blockIdx.x * chunkE;
    const int e = min(s + chunkE, E);

    for (int i = tid; i < nsb; i += 256) hist[i] = 0;
    __syncthreads();
    for (int j = s + tid; j < e; j += 256) atomicAdd(&hist[col[j] >> SBSH], 1);
    __syncthreads();
    for (int i = tid; i < nsb; i += 256) {
        int h = hist[i];
        lcur[i] = h ? atomicAdd(&cursorB[i], h) : 0;
    }
    __syncthreads();
    for (int j = s + tid; j < e; j += 256) {
        int c = col[j];
        int pos = atomicAdd(&lcur[c >> SBSH], 1);
        part[pos] = (row[j] << SBSH) | (c & (SBN - 1));
    }
}

// 6) within-super-bucket counting sort -> eRow grouped by destination node.
//    Block owns its bucket: LDS cursors, private contiguous output range.
__global__ void __launch_bounds__(256) k_binsort(const int* __restrict__ rowptr,
                                                 const int* __restrict__ part,
                                                 int* __restrict__ eRow, int N, int E) {
    __shared__ int lbase[SBN];
    __shared__ int lcur[SBN];
    const int base = blockIdx.x << SBSH;
    {
        int n = base + threadIdx.x;
        lbase[threadIdx.x] = (n <= N) ? rowptr[n] : E;  // rowptr[N] = E
        lcur[threadIdx.x] = 0;
    }
    __syncthreads();
    const int s = rowptr[base];
    const int e = (base + SBN <= N) ? rowptr[base + SBN] : E;
    for (int j = s + threadIdx.x; j < e; j += 256) {
        int p = part[j];
        int nl = p & (SBN - 1);
        int pos = lbase[nl] + atomicAdd(&lcur[nl], 1);
        eRow[pos] = p >> SBSH;
    }
}

// 7) gather-aggregate: half-wave (32 lanes) per node, lane = uint (2 bf16 cols).
//    out[n] = relu(dinv[n]*(xs[n] + sum xs[nbr]) + b), fp32 math, plain writes.
__global__ void __launch_bounds__(256) k_agg(const int* __restrict__ rowptr,
                                             const int* __restrict__ eRow,
                                             const unsigned* __restrict__ xsb,
                                             const float* __restrict__ dinv,
                                             const float* __restrict__ bias,
                                             float* __restrict__ out, int N) {
    const int lane = threadIdx.x & 63;
    const int l = lane & 31;
    const int n = (blockIdx.x * 4 + (threadIdx.x >> 6)) * 2 + (lane >> 5);
    if (n >= N) return;

    const int s = rowptr[n];
    const int e = rowptr[n + 1];

    unsigned u = xsb[(size_t)n * 32 + l];  // self-loop term
    float ax = __uint_as_float(u << 16), ay = __uint_as_float(u & 0xffff0000u);
    float b0x = 0.f, b0y = 0.f, b1x = 0.f, b1y = 0.f;
    float b2x = 0.f, b2y = 0.f, b3x = 0.f, b3y = 0.f;
    int j = s;
    for (; j + 3 < e; j += 4) {
        unsigned u0 = xsb[(size_t)eRow[j] * 32 + l];
        unsigned u1 = xsb[(size_t)eRow[j + 1] * 32 + l];
        unsigned u2 = xsb[(size_t)eRow[j + 2] * 32 + l];
        unsigned u3 = xsb[(size_t)eRow[j + 3] * 32 + l];
        b0x += __uint_as_float(u0 << 16); b0y += __uint_as_float(u0 & 0xffff0000u);
        b1x += __uint_as_float(u1 << 16); b1y += __uint_as_float(u1 & 0xffff0000u);
        b2x += __uint_as_float(u2 << 16); b2y += __uint_as_float(u2 & 0xffff0000u);
        b3x += __uint_as_float(u3 << 16); b3y += __uint_as_float(u3 & 0xffff0000u);
    }
    for (; j < e; ++j) {
        unsigned u0 = xsb[(size_t)eRow[j] * 32 + l];
        ax += __uint_as_float(u0 << 16); ay += __uint_as_float(u0 & 0xffff0000u);
    }
    ax += (b0x + b1x) + (b2x + b3x);
    ay += (b0y + b1y) + (b2y + b3y);

    const float d = dinv[n];
    const float2 bl = *(const float2*)&bias[2 * l];
    float2 o;
    o.x = fmaxf(fmaf(ax, d, bl.x), 0.f);
    o.y = fmaxf(fmaf(ay, d, bl.y), 0.f);
    *(float2*)(out + (size_t)n * HID + 2 * l) = o;
}

extern "C" void kernel_launch(void* const* d_in, const int* in_sizes, int n_in,
                              void* d_out, int out_size, void* d_ws, size_t ws_size,
                              hipStream_t stream) {
    const float* x  = (const float*)d_in[0];
    const int*   ei = (const int*)d_in[1];
    const float* W  = (const float*)d_in[2];
    const float* b  = (const float*)d_in[3];
    float* out = (float*)d_out;

    const int N = in_sizes[0] / IN_DIM;
    const int E = in_sizes[1] / 2;
    const int* row = ei;      // edge_index[0] = sources
    const int* col = ei + E;  // edge_index[1] = destinations
    const int NSB = (N + SBN - 1) >> SBSH;
    const int nch = (N + CHUNK - 1) / CHUNK;

    // workspace (4-byte units), ~40 MB:
    // cnt[N] | pscan[N] | rowptr[N+1] | cursorB[NSB] | chunkSum[64] | chunkOff[64]
    // | dinv[N] | xsb[N*32] | part[E] | eRow[E]
    int*      cnt      = (int*)d_ws;
    int*      pscan    = cnt + N;
    int*      rowptr   = pscan + N;
    int*      cursorB  = rowptr + (N + 1);
    int*      chunkSum = cursorB + NSB;
    int*      chunkOff = chunkSum + 64;
    float*    dinv     = (float*)(chunkOff + 64);
    unsigned* xsb      = (unsigned*)(dinv + N);
    int*      part     = (int*)(xsb + (size_t)N * (HID / 2));
    int*      eRow     = part + E;

    k_zero<<<(N + 255) / 256, 256, 0, stream>>>(cnt, N);
    k_hist<<<2048, 256, 0, stream>>>(col, cnt, E);
    k_scan1<<<nch, 256, 0, stream>>>(cnt, pscan, chunkSum, N);
    k_scan2<<<1, 64, 0, stream>>>(chunkSum, chunkOff, nch);
    k_scan3<<<(N + 255) / 256, 256, 0, stream>>>(cnt, pscan, chunkOff, rowptr, cursorB, dinv, N, E);
    k_gemm<<<(N + 255) / 256, 256, 0, stream>>>(x, W, dinv, xsb, N);
    k_part2<<<256, 256, 0, stream>>>(row, col, cursorB, part, E, NSB);
    k_binsort<<<NSB, 256, 0, stream>>>(rowptr, part, eRow, N, E);
    k_agg<<<(N + 7) / 8, 256, 0, stream>>>(rowptr, eRow, xsb, dinv, b, out, N);
}

// Round 7
// 415.140 us; speedup vs baseline: 4.7573x; 1.2575x over previous
//
#include <hip/hip_runtime.h>

#define IN_DIM 256
#define HID 64
#define SBSH 8             // log2(nodes per super-bucket)
#define SBN 256            // nodes per super-bucket
#define NSB_MAX 512        // LDS array bound (covers N <= 131072)

// round-to-nearest-even fp32 -> bf16 bits
static __device__ __forceinline__ unsigned bf16r(float f) {
    unsigned x = __float_as_uint(f);
    return (x + 0x7fffu + ((x >> 16) & 1u)) >> 16;
}

// ---------------------------------------------------------------------------
// 1) zero the coarse bucket counters (tiny)
__global__ void __launch_bounds__(256) k_zero(int* __restrict__ p, int n) {
    int i = blockIdx.x * 256 + threadIdx.x;
    if (i < n) p[i] = 0;
}

// 2) coarse histogram: per-block LDS hist over 391 super-buckets,
//    one global atomicAdd per (block,bucket) (~100K total vs 3.2M fine).
__global__ void __launch_bounds__(256) k_chist(const int* __restrict__ col,
                                               int* __restrict__ bucketCnt, int E, int nsb) {
    __shared__ int hist[NSB_MAX];
    const int tid = threadIdx.x;
    const int chunkE = (E + gridDim.x - 1) / gridDim.x;
    const int s = blockIdx.x * chunkE;
    const int e = min(s + chunkE, E);
    for (int i = tid; i < nsb; i += 256) hist[i] = 0;
    __syncthreads();
    for (int j = s + tid; j < e; j += 256) atomicAdd(&hist[col[j] >> SBSH], 1);
    __syncthreads();
    for (int i = tid; i < nsb; i += 256) {
        int h = hist[i];
        if (h) atomicAdd(&bucketCnt[i], h);
    }
}

// 3) single-block exclusive scan of bucketCnt[nsb] -> bucketOff, cursorB;
//    also seeds rowptr[N] = E.
__global__ void __launch_bounds__(256) k_scanB(const int* __restrict__ bucketCnt,
                                               int* __restrict__ bucketOff,
                                               int* __restrict__ cursorB,
                                               int* __restrict__ rowptr,
                                               int nsb, int N, int E) {
    __shared__ int tmp[256];
    const int tid = threadIdx.x;
    const int PT = (nsb + 255) >> 8;  // <= 2 for N <= 131072
    int v[8];
    int s = 0;
    for (int k = 0; k < PT; ++k) {
        int i = tid * PT + k;
        v[k] = (i < nsb) ? bucketCnt[i] : 0;
        s += v[k];
    }
    tmp[tid] = s;
    __syncthreads();
    for (int d = 1; d < 256; d <<= 1) {  // Hillis-Steele inclusive scan
        int val = (tid >= d) ? tmp[tid - d] : 0;
        __syncthreads();
        tmp[tid] += val;
        __syncthreads();
    }
    int run = tmp[tid] - s;
    for (int k = 0; k < PT; ++k) {
        int i = tid * PT + k;
        if (i < nsb) { bucketOff[i] = run; cursorB[i] = run; }
        run += v[k];
    }
    if (tid == 255) { bucketOff[nsb] = E; rowptr[N] = E; }
}

// 4) two-pass per-block LDS-histogram partition into 256-node super-buckets.
//    part[pos] = (row << 8) | (col & 255); runs are single-writer, L2-local.
__global__ void __launch_bounds__(256) k_part2(const int* __restrict__ row,
                                               const int* __restrict__ col,
                                               int* __restrict__ cursorB,
                                               int* __restrict__ part, int E, int nsb) {
    __shared__ int hist[NSB_MAX];
    __shared__ int lcur[NSB_MAX];
    const int tid = threadIdx.x;
    const int chunkE = (E + gridDim.x - 1) / gridDim.x;
    const int s = blockIdx.x * chunkE;
    const int e = min(s + chunkE, E);

    for (int i = tid; i < nsb; i += 256) hist[i] = 0;
    __syncthreads();
    for (int j = s + tid; j < e; j += 256) atomicAdd(&hist[col[j] >> SBSH], 1);
    __syncthreads();
    for (int i = tid; i < nsb; i += 256) {
        int h = hist[i];
        lcur[i] = h ? atomicAdd(&cursorB[i], h) : 0;
    }
    __syncthreads();
    for (int j = s + tid; j < e; j += 256) {
        int c = col[j];
        int pos = atomicAdd(&lcur[c >> SBSH], 1);
        part[pos] = (row[j] << SBSH) | (c & (SBN - 1));
    }
}

// 5) within-bucket: LDS per-node histogram -> local scan -> rowptr + dinv +
//    counting sort into eRow. Block owns its bucket; no global atomics.
__global__ void __launch_bounds__(256) k_sortb(const int* __restrict__ bucketOff,
                                               const int* __restrict__ part,
                                               int* __restrict__ rowptr,
                                               float* __restrict__ dinv,
                                               int* __restrict__ eRow, int N) {
    __shared__ int hcnt[SBN];
    __shared__ int tmp[SBN];
    __shared__ int cur[SBN];
    const int tid = threadIdx.x;
    const int base = blockIdx.x << SBSH;
    const int s = bucketOff[blockIdx.x];
    const int e = bucketOff[blockIdx.x + 1];

    hcnt[tid] = 0;
    __syncthreads();
    for (int j = s + tid; j < e; j += 256) atomicAdd(&hcnt[part[j] & (SBN - 1)], 1);
    __syncthreads();
    const int c = hcnt[tid];
    tmp[tid] = c;
    __syncthreads();
    for (int d = 1; d < 256; d <<= 1) {  // Hillis-Steele inclusive scan
        int val = (tid >= d) ? tmp[tid - d] : 0;
        __syncthreads();
        tmp[tid] += val;
        __syncthreads();
    }
    const int myBase = s + tmp[tid] - c;  // exclusive
    cur[tid] = myBase;
    const int n = base + tid;
    if (n < N) {
        rowptr[n] = myBase;
        dinv[n] = __frsqrt_rn((float)(c + 1));
    }
    __syncthreads();
    for (int j = s + tid; j < e; j += 256) {
        int p = part[j];
        int pos = atomicAdd(&cur[p & (SBN - 1)], 1);
        eRow[pos] = p >> SBSH;
    }
}

// 6) xs = (x @ W) * dinv[n]  — register-tiled fp32 GEMM; epilogue packs bf16x2.
__global__ void __launch_bounds__(256) k_gemm(const float* __restrict__ x,
                                              const float* __restrict__ W,
                                              const float* __restrict__ dinv,
                                              unsigned* __restrict__ xsb, int N) {
    __shared__ float xT[32][260];
    __shared__ float Wl[32][64];
    const int t = threadIdx.x;
    const int tmI = t >> 3;
    const int tnI = t & 7;
    const int nodeBase = blockIdx.x * 256;

    float acc[8][8] = {};

    for (int k0 = 0; k0 < IN_DIM; k0 += 32) {
#pragma unroll
        for (int i = 0; i < 2; ++i) {
            int flat = i * 256 + t;
            float4 wv = ((const float4*)W)[k0 * 16 + flat];
            *(float4*)&Wl[flat >> 4][(flat & 15) << 2] = wv;
        }
#pragma unroll
        for (int i = 0; i < 8; ++i) {
            int flat = i * 256 + t;
            int n = flat >> 3;
            int kq = (flat & 7) << 2;
            int gn = nodeBase + n;
            if (gn >= N) gn = N - 1;
            float4 v = *(const float4*)(x + (size_t)gn * IN_DIM + k0 + kq);
            xT[kq + 0][n] = v.x;
            xT[kq + 1][n] = v.y;
            xT[kq + 2][n] = v.z;
            xT[kq + 3][n] = v.w;
        }
        __syncthreads();
#pragma unroll
        for (int k = 0; k < 32; ++k) {
            float xv[8], wv[8];
            *(float4*)&xv[0] = *(const float4*)&xT[k][tmI * 8];
            *(float4*)&xv[4] = *(const float4*)&xT[k][tmI * 8 + 4];
            *(float4*)&wv[0] = *(const float4*)&Wl[k][tnI * 8];
            *(float4*)&wv[4] = *(const float4*)&Wl[k][tnI * 8 + 4];
#pragma unroll
            for (int mi = 0; mi < 8; ++mi)
#pragma unroll
                for (int ni = 0; ni < 8; ++ni)
                    acc[mi][ni] = fmaf(xv[mi], wv[ni], acc[mi][ni]);
        }
        __syncthreads();
    }

#pragma unroll
    for (int mi = 0; mi < 8; ++mi) {
        int n = nodeBase + tmI * 8 + mi;
        if (n < N) {
            float d = dinv[n];
            uint4 o;
            o.x = bf16r(acc[mi][0] * d) | (bf16r(acc[mi][1] * d) << 16);
            o.y = bf16r(acc[mi][2] * d) | (bf16r(acc[mi][3] * d) << 16);
            o.z = bf16r(acc[mi][4] * d) | (bf16r(acc[mi][5] * d) << 16);
            o.w = bf16r(acc[mi][6] * d) | (bf16r(acc[mi][7] * d) << 16);
            *(uint4*)(xsb + (size_t)n * (HID / 2) + tnI * 4) = o;
        }
    }
}

// 7) gather-aggregate: half-wave (32 lanes) per node, lane = uint (2 bf16 cols).
__global__ void __launch_bounds__(256) k_agg(const int* __restrict__ rowptr,
                                             const int* __restrict__ eRow,
                                             const unsigned* __restrict__ xsb,
                                             const float* __restrict__ dinv,
                                             const float* __restrict__ bias,
                                             float* __restrict__ out, int N) {
    const int lane = threadIdx.x & 63;
    const int l = lane & 31;
    const int n = (blockIdx.x * 4 + (threadIdx.x >> 6)) * 2 + (lane >> 5);
    if (n >= N) return;

    const int s = rowptr[n];
    const int e = rowptr[n + 1];

    unsigned u = xsb[(size_t)n * 32 + l];  // self-loop term
    float ax = __uint_as_float(u << 16), ay = __uint_as_float(u & 0xffff0000u);
    float b0x = 0.f, b0y = 0.f, b1x = 0.f, b1y = 0.f;
    float b2x = 0.f, b2y = 0.f, b3x = 0.f, b3y = 0.f;
    int j = s;
    for (; j + 3 < e; j += 4) {
        unsigned u0 = xsb[(size_t)eRow[j] * 32 + l];
        unsigned u1 = xsb[(size_t)eRow[j + 1] * 32 + l];
        unsigned u2 = xsb[(size_t)eRow[j + 2] * 32 + l];
        unsigned u3 = xsb[(size_t)eRow[j + 3] * 32 + l];
        b0x += __uint_as_float(u0 << 16); b0y += __uint_as_float(u0 & 0xffff0000u);
        b1x += __uint_as_float(u1 << 16); b1y += __uint_as_float(u1 & 0xffff0000u);
        b2x += __uint_as_float(u2 << 16); b2y += __uint_as_float(u2 & 0xffff0000u);
        b3x += __uint_as_float(u3 << 16); b3y += __uint_as_float(u3 & 0xffff0000u);
    }
    for (; j < e; ++j) {
        unsigned u0 = xsb[(size_t)eRow[j] * 32 + l];
        ax += __uint_as_float(u0 << 16); ay += __uint_as_float(u0 & 0xffff0000u);
    }
    ax += (b0x + b1x) + (b2x + b3x);
    ay += (b0y + b1y) + (b2y + b3y);

    const float d = dinv[n];
    const float2 bl = *(const float2*)&bias[2 * l];
    float2 o;
    o.x = fmaxf(fmaf(ax, d, bl.x), 0.f);
    o.y = fmaxf(fmaf(ay, d, bl.y), 0.f);
    *(float2*)(out + (size_t)n * HID + 2 * l) = o;
}

extern "C" void kernel_launch(void* const* d_in, const int* in_sizes, int n_in,
                              void* d_out, int out_size, void* d_ws, size_t ws_size,
                              hipStream_t stream) {
    const float* x  = (const float*)d_in[0];
    const int*   ei = (const int*)d_in[1];
    const float* W  = (const float*)d_in[2];
    const float* b  = (const float*)d_in[3];
    float* out = (float*)d_out;

    const int N = in_sizes[0] / IN_DIM;
    const int E = in_sizes[1] / 2;
    const int* row = ei;      // edge_index[0] = sources
    const int* col = ei + E;  // edge_index[1] = destinations
    const int NSB = (N + SBN - 1) >> SBSH;

    // workspace (4-byte units), ~39 MB:
    // bucketCnt[NSB] | bucketOff[NSB+1] | cursorB[NSB] | rowptr[N+1] | dinv[N]
    // | xsb[N*32] | part[E] | eRow[E]
    int*      bucketCnt = (int*)d_ws;
    int*      bucketOff = bucketCnt + NSB;
    int*      cursorB   = bucketOff + NSB + 1;
    int*      rowptr    = cursorB + NSB;
    float*    dinv      = (float*)(rowptr + N + 1);
    unsigned* xsb       = (unsigned*)(dinv + N);
    int*      part      = (int*)(xsb + (size_t)N * (HID / 2));
    int*      eRow      = part + E;

    k_zero<<<(NSB + 255) / 256, 256, 0, stream>>>(bucketCnt, NSB);
    k_chist<<<256, 256, 0, stream>>>(col, bucketCnt, E, NSB);
    k_scanB<<<1, 256, 0, stream>>>(bucketCnt, bucketOff, cursorB, rowptr, NSB, N, E);
    k_part2<<<256, 256, 0, stream>>>(row, col, cursorB, part, E, NSB);
    k_sortb<<<NSB, 256, 0, stream>>>(bucketOff, part, rowptr, dinv, eRow, N);
    k_gemm<<<(N + 255) / 256, 256, 0, stream>>>(x, W, dinv, xsb, N);
    k_agg<<<(N + 7) / 8, 256, 0, stream>>>(rowptr, eRow, xsb, dinv, b, out, N);
}

// Round 8
// 401.519 us; speedup vs baseline: 4.9187x; 1.0339x over previous
//
#include <hip/hip_runtime.h>

#define IN_DIM 256
#define HID 64
#define SBSH 8             // log2(nodes per super-bucket)
#define SBN 256            // nodes per super-bucket
#define NSB_MAX 512        // LDS array bound (covers N <= 131072)
#define PB 256             // partition blocks (chunk count) — must match p2a/p2b

// round-to-nearest-even fp32 -> bf16 bits
static __device__ __forceinline__ unsigned bf16r(float f) {
    unsigned x = __float_as_uint(f);
    return (x + 0x7fffu + ((x >> 16) & 1u)) >> 16;
}

static __device__ __forceinline__ float blo(unsigned u) { return __uint_as_float(u << 16); }
static __device__ __forceinline__ float bhi(unsigned u) { return __uint_as_float(u & 0xffff0000u); }

// ---------------------------------------------------------------------------
// 1) zero the coarse bucket counters (tiny)
__global__ void __launch_bounds__(256) k_zero(int* __restrict__ p, int n) {
    int i = blockIdx.x * 256 + threadIdx.x;
    if (i < n) p[i] = 0;
}

// 2) partition pass A: per-block LDS histogram over super-buckets.
//    Stores blkHist[bucket][block] and accumulates bucketCnt (one atomic per
//    (block,bucket) ~ 100K total). Single edge-list read.
__global__ void __launch_bounds__(256) k_p2a(const int* __restrict__ col,
                                             int* __restrict__ bucketCnt,
                                             int* __restrict__ blkHist, int E, int nsb) {
    __shared__ int hist[NSB_MAX];
    const int tid = threadIdx.x, b = blockIdx.x;
    const int chunkE = (E + PB - 1) / PB;
    const int s = b * chunkE, e = min(s + chunkE, E);
    for (int i = tid; i < nsb; i += 256) hist[i] = 0;
    __syncthreads();
    for (int j = s + tid; j < e; j += 256) atomicAdd(&hist[col[j] >> SBSH], 1);
    __syncthreads();
    for (int i = tid; i < nsb; i += 256) {
        int h = hist[i];
        blkHist[i * PB + b] = h;
        if (h) atomicAdd(&bucketCnt[i], h);
    }
}

// 3) single-block exclusive scan of bucketCnt[nsb] -> bucketOff; seeds rowptr[N]=E.
__global__ void __launch_bounds__(256) k_scanB(const int* __restrict__ bucketCnt,
                                               int* __restrict__ bucketOff,
                                               int* __restrict__ rowptr,
                                               int nsb, int N, int E) {
    __shared__ int tmp[256];
    const int tid = threadIdx.x;
    const int PT = (nsb + 255) >> 8;
    int v[8];
    int s = 0;
    for (int k = 0; k < PT; ++k) {
        int i = tid * PT + k;
        v[k] = (i < nsb) ? bucketCnt[i] : 0;
        s += v[k];
    }
    tmp[tid] = s;
    __syncthreads();
    for (int d = 1; d < 256; d <<= 1) {  // Hillis-Steele inclusive scan
        int val = (tid >= d) ? tmp[tid - d] : 0;
        __syncthreads();
        tmp[tid] += val;
        __syncthreads();
    }
    int run = tmp[tid] - s;
    for (int k = 0; k < PT; ++k) {
        int i = tid * PT + k;
        if (i < nsb) bucketOff[i] = run;
        run += v[k];
    }
    if (tid == 255) { bucketOff[nsb] = E; rowptr[N] = E; }
}

// 4) per-bucket scan over PB block-histogram entries -> absolute block cursors.
//    block i: blkCur[i][b] = bucketOff[i] + sum_{b'<b} blkHist[i][b'].
__global__ void __launch_bounds__(256) k_scanBlk(const int* __restrict__ bucketOff,
                                                 const int* __restrict__ blkHist,
                                                 int* __restrict__ blkCur) {
    __shared__ int tmp[PB];
    const int i = blockIdx.x, t = threadIdx.x;
    int v = blkHist[i * PB + t];
    tmp[t] = v;
    __syncthreads();
    for (int d = 1; d < PB; d <<= 1) {
        int val = (t >= d) ? tmp[t - d] : 0;
        __syncthreads();
        tmp[t] += val;
        __syncthreads();
    }
    blkCur[i * PB + t] = bucketOff[i] + tmp[t] - v;
}

// 5) partition pass B: scatter with LDS cursors preloaded from blkCur.
//    No global atomics at all; part[pos] = (row << 8) | (col & 255).
__global__ void __launch_bounds__(256) k_p2b(const int* __restrict__ row,
                                             const int* __restrict__ col,
                                             const int* __restrict__ blkCur,
                                             int* __restrict__ part, int E, int nsb) {
    __shared__ int lcur[NSB_MAX];
    const int tid = threadIdx.x, b = blockIdx.x;
    const int chunkE = (E + PB - 1) / PB;
    const int s = b * chunkE, e = min(s + chunkE, E);
    for (int i = tid; i < nsb; i += 256) lcur[i] = blkCur[i * PB + b];
    __syncthreads();
    for (int j = s + tid; j < e; j += 256) {
        int c = col[j];
        int pos = atomicAdd(&lcur[c >> SBSH], 1);
        part[pos] = (row[j] << SBSH) | (c & (SBN - 1));
    }
}

// 6) within-bucket: LDS per-node histogram -> local scan -> rowptr + dinv +
//    counting sort into eRow. Block owns its bucket; no global atomics.
__global__ void __launch_bounds__(256) k_sortb(const int* __restrict__ bucketOff,
                                               const int* __restrict__ part,
                                               int* __restrict__ rowptr,
                                               float* __restrict__ dinv,
                                               int* __restrict__ eRow, int N) {
    __shared__ int hcnt[SBN];
    __shared__ int tmp[SBN];
    __shared__ int cur[SBN];
    const int tid = threadIdx.x;
    const int base = blockIdx.x << SBSH;
    const int s = bucketOff[blockIdx.x];
    const int e = bucketOff[blockIdx.x + 1];

    hcnt[tid] = 0;
    __syncthreads();
    for (int j = s + tid; j < e; j += 256) atomicAdd(&hcnt[part[j] & (SBN - 1)], 1);
    __syncthreads();
    const int c = hcnt[tid];
    tmp[tid] = c;
    __syncthreads();
    for (int d = 1; d < 256; d <<= 1) {  // Hillis-Steele inclusive scan
        int val = (tid >= d) ? tmp[tid - d] : 0;
        __syncthreads();
        tmp[tid] += val;
        __syncthreads();
    }
    const int myBase = s + tmp[tid] - c;  // exclusive
    cur[tid] = myBase;
    const int n = base + tid;
    if (n < N) {
        rowptr[n] = myBase;
        dinv[n] = __frsqrt_rn((float)(c + 1));
    }
    __syncthreads();
    for (int j = s + tid; j < e; j += 256) {
        int p = part[j];
        int pos = atomicAdd(&cur[p & (SBN - 1)], 1);
        eRow[pos] = p >> SBSH;
    }
}

// 7) xs = (x @ W) * dinv[n]  — register-tiled fp32 GEMM; epilogue packs bf16x2.
__global__ void __launch_bounds__(256) k_gemm(const float* __restrict__ x,
                                              const float* __restrict__ W,
                                              const float* __restrict__ dinv,
                                              unsigned* __restrict__ xsb, int N) {
    __shared__ float xT[32][260];
    __shared__ float Wl[32][64];
    const int t = threadIdx.x;
    const int tmI = t >> 3;
    const int tnI = t & 7;
    const int nodeBase = blockIdx.x * 256;

    float acc[8][8] = {};

    for (int k0 = 0; k0 < IN_DIM; k0 += 32) {
#pragma unroll
        for (int i = 0; i < 2; ++i) {
            int flat = i * 256 + t;
            float4 wv = ((const float4*)W)[k0 * 16 + flat];
            *(float4*)&Wl[flat >> 4][(flat & 15) << 2] = wv;
        }
#pragma unroll
        for (int i = 0; i < 8; ++i) {
            int flat = i * 256 + t;
            int n = flat >> 3;
            int kq = (flat & 7) << 2;
            int gn = nodeBase + n;
            if (gn >= N) gn = N - 1;
            float4 v = *(const float4*)(x + (size_t)gn * IN_DIM + k0 + kq);
            xT[kq + 0][n] = v.x;
            xT[kq + 1][n] = v.y;
            xT[kq + 2][n] = v.z;
            xT[kq + 3][n] = v.w;
        }
        __syncthreads();
#pragma unroll
        for (int k = 0; k < 32; ++k) {
            float xv[8], wv[8];
            *(float4*)&xv[0] = *(const float4*)&xT[k][tmI * 8];
            *(float4*)&xv[4] = *(const float4*)&xT[k][tmI * 8 + 4];
            *(float4*)&wv[0] = *(const float4*)&Wl[k][tnI * 8];
            *(float4*)&wv[4] = *(const float4*)&Wl[k][tnI * 8 + 4];
#pragma unroll
            for (int mi = 0; mi < 8; ++mi)
#pragma unroll
                for (int ni = 0; ni < 8; ++ni)
                    acc[mi][ni] = fmaf(xv[mi], wv[ni], acc[mi][ni]);
        }
        __syncthreads();
    }

#pragma unroll
    for (int mi = 0; mi < 8; ++mi) {
        int n = nodeBase + tmI * 8 + mi;
        if (n < N) {
            float d = dinv[n];
            uint4 o;
            o.x = bf16r(acc[mi][0] * d) | (bf16r(acc[mi][1] * d) << 16);
            o.y = bf16r(acc[mi][2] * d) | (bf16r(acc[mi][3] * d) << 16);
            o.z = bf16r(acc[mi][4] * d) | (bf16r(acc[mi][5] * d) << 16);
            o.w = bf16r(acc[mi][6] * d) | (bf16r(acc[mi][7] * d) << 16);
            *(uint4*)(xsb + (size_t)n * (HID / 2) + tnI * 4) = o;
        }
    }
}

// 8) gather-aggregate: half-wave (32 lanes) per node, lane = uint (2 bf16 cols),
//    8-deep gather ILP.
__global__ void __launch_bounds__(256) k_agg(const int* __restrict__ rowptr,
                                             const int* __restrict__ eRow,
                                             const unsigned* __restrict__ xsb,
                                             const float* __restrict__ dinv,
                                             const float* __restrict__ bias,
                                             float* __restrict__ out, int N) {
    const int lane = threadIdx.x & 63;
    const int l = lane & 31;
    const int n = (blockIdx.x * 4 + (threadIdx.x >> 6)) * 2 + (lane >> 5);
    if (n >= N) return;

    const int s = rowptr[n];
    const int e = rowptr[n + 1];

    unsigned u = xsb[(size_t)n * 32 + l];  // self-loop term
    float ax = blo(u), ay = bhi(u);
    float b0x = 0.f, b0y = 0.f, b1x = 0.f, b1y = 0.f;
    float b2x = 0.f, b2y = 0.f, b3x = 0.f, b3y = 0.f;
    int j = s;
    for (; j + 7 < e; j += 8) {
        int r0 = eRow[j],     r1 = eRow[j + 1], r2 = eRow[j + 2], r3 = eRow[j + 3];
        int r4 = eRow[j + 4], r5 = eRow[j + 5], r6 = eRow[j + 6], r7 = eRow[j + 7];
        unsigned u0 = xsb[(size_t)r0 * 32 + l];
        unsigned u1 = xsb[(size_t)r1 * 32 + l];
        unsigned u2 = xsb[(size_t)r2 * 32 + l];
        unsigned u3 = xsb[(size_t)r3 * 32 + l];
        unsigned u4 = xsb[(size_t)r4 * 32 + l];
        unsigned u5 = xsb[(size_t)r5 * 32 + l];
        unsigned u6 = xsb[(size_t)r6 * 32 + l];
        unsigned u7 = xsb[(size_t)r7 * 32 + l];
        b0x += blo(u0); b0y += bhi(u0);
        b1x += blo(u1); b1y += bhi(u1);
        b2x += blo(u2); b2y += bhi(u2);
        b3x += blo(u3); b3y += bhi(u3);
        b0x += blo(u4); b0y += bhi(u4);
        b1x += blo(u5); b1y += bhi(u5);
        b2x += blo(u6); b2y += bhi(u6);
        b3x += blo(u7); b3y += bhi(u7);
    }
    for (; j + 3 < e; j += 4) {
        int r0 = eRow[j], r1 = eRow[j + 1], r2 = eRow[j + 2], r3 = eRow[j + 3];
        unsigned u0 = xsb[(size_t)r0 * 32 + l];
        unsigned u1 = xsb[(size_t)r1 * 32 + l];
        unsigned u2 = xsb[(size_t)r2 * 32 + l];
        unsigned u3 = xsb[(size_t)r3 * 32 + l];
        b0x += blo(u0); b0y += bhi(u0);
        b1x += blo(u1); b1y += bhi(u1);
        b2x += blo(u2); b2y += bhi(u2);
        b3x += blo(u3); b3y += bhi(u3);
    }
    for (; j < e; ++j) {
        unsigned u0 = xsb[(size_t)eRow[j] * 32 + l];
        ax += blo(u0); ay += bhi(u0);
    }
    ax += (b0x + b1x) + (b2x + b3x);
    ay += (b0y + b1y) + (b2y + b3y);

    const float d = dinv[n];
    const float2 bl = *(const float2*)&bias[2 * l];
    float2 o;
    o.x = fmaxf(fmaf(ax, d, bl.x), 0.f);
    o.y = fmaxf(fmaf(ay, d, bl.y), 0.f);
    *(float2*)(out + (size_t)n * HID + 2 * l) = o;
}

extern "C" void kernel_launch(void* const* d_in, const int* in_sizes, int n_in,
                              void* d_out, int out_size, void* d_ws, size_t ws_size,
                              hipStream_t stream) {
    const float* x  = (const float*)d_in[0];
    const int*   ei = (const int*)d_in[1];
    const float* W  = (const float*)d_in[2];
    const float* b  = (const float*)d_in[3];
    float* out = (float*)d_out;

    const int N = in_sizes[0] / IN_DIM;
    const int E = in_sizes[1] / 2;
    const int* row = ei;      // edge_index[0] = sources
    const int* col = ei + E;  // edge_index[1] = destinations
    const int NSB = (N + SBN - 1) >> SBSH;

    // workspace (4-byte units), ~41 MB:
    // bucketCnt[NSB] | bucketOff[NSB+1] | rowptr[N+1] | dinv[N] | xsb[N*32]
    // | part[E] | eRow[E] | blkHist[NSB*PB] | blkCur[NSB*PB]
    int*      bucketCnt = (int*)d_ws;
    int*      bucketOff = bucketCnt + NSB;
    int*      rowptr    = bucketOff + NSB + 1;
    float*    dinv      = (float*)(rowptr + N + 1);
    unsigned* xsb       = (unsigned*)(dinv + N);
    int*      part      = (int*)(xsb + (size_t)N * (HID / 2));
    int*      eRow      = part + E;
    int*      blkHist   = eRow + E;
    int*      blkCur    = blkHist + NSB * PB;

    k_zero<<<(NSB + 255) / 256, 256, 0, stream>>>(bucketCnt, NSB);
    k_p2a<<<PB, 256, 0, stream>>>(col, bucketCnt, blkHist, E, NSB);
    k_scanB<<<1, 256, 0, stream>>>(bucketCnt, bucketOff, rowptr, NSB, N, E);
    k_scanBlk<<<NSB, PB, 0, stream>>>(bucketOff, blkHist, blkCur);
    k_p2b<<<PB, 256, 0, stream>>>(row, col, blkCur, part, E, NSB);
    k_sortb<<<NSB, 256, 0, stream>>>(bucketOff, part, rowptr, dinv, eRow, N);
    k_gemm<<<(N + 255) / 256, 256, 0, stream>>>(x, W, dinv, xsb, N);
    k_agg<<<(N + 7) / 8, 256, 0, stream>>>(rowptr, eRow, xsb, dinv, b, out, N);
}